// Round 7
// baseline (12561.781 us; speedup 1.0000x reference)
//
#include <hip/hip_runtime.h>
#include <cstddef>

// ---------------------------------------------------------------------------
// TrainModel: CNN -> BiLSTM encoder -> attention decoder.
// B=16, image 64x512x1, Hp=8, Wp=64, ENC_H=256, DEC_H=512, ATT=512, VOCAB=504
// Round 7: fix round-5 aliasing bug (henc[0] memset was inside c3, clobbered
// by conv3).  Encoder now treats h0=0 analytically via `if (t>0)` guard; no
// henc[0] init needed.  Keeps single-hop barriers + fp32 Wcat LDS + fences.
// ---------------------------------------------------------------------------

#define TDEC 150
#define TLAB 151
typedef unsigned short u16;

__device__ __forceinline__ float sigm(float x) { return 1.0f / (1.0f + __expf(-x)); }
__device__ __forceinline__ float tanhfast(float x) {
  float ax = fabsf(x);
  float e = __expf(-2.0f * ax);
  float t = (1.0f - e) / (1.0f + e);
  return x < 0.0f ? -t : t;
}
__device__ __forceinline__ int EZX(int d) { return ((d & 63) << 3) | (d >> 6); }

__device__ __forceinline__ unsigned ld_cg(const unsigned* p) {
  return __hip_atomic_load(p, __ATOMIC_RELAXED, __HIP_MEMORY_SCOPE_AGENT);
}
__device__ __forceinline__ void st_cg(unsigned* p, unsigned v) {
  __hip_atomic_store(p, v, __ATOMIC_RELAXED, __HIP_MEMORY_SCOPE_AGENT);
}
__device__ __forceinline__ void stf_cg(float* p, float v) {
  __hip_atomic_store(p, v, __ATOMIC_RELAXED, __HIP_MEMORY_SCOPE_AGENT);
}
__device__ __forceinline__ void acq_fence() {
  __builtin_amdgcn_fence(__ATOMIC_ACQUIRE, "agent");   // L1 invalidate
}
__device__ __forceinline__ float bfhi(unsigned x) { return __uint_as_float(x & 0xFFFF0000u); }
__device__ __forceinline__ float bflo(unsigned x) { return __uint_as_float(x << 16); }

// ---------------- conv1: fused conv3x3 + relu + pool -----------------------
__global__ __launch_bounds__(256) void conv_pool(
    const float* __restrict__ x, const float* __restrict__ W,
    const float* __restrict__ bias, float* __restrict__ y,
    int Hin, int Win, int Cin, int Cout)
{
  int Hout = Hin >> 1, Wout = Win >> 1;
  int cg = Cout >> 3;
  int idx = blockIdx.x * 256 + threadIdx.x;
  int total = 16 * Hout * Wout * cg;
  if (idx >= total) return;
  int g = idx % cg; int r = idx / cg;
  int pw = r % Wout; r /= Wout;
  int ph = r % Hout; int b = r / Hout;
  int co = g * 8;
  int h0 = ph * 2, w0 = pw * 2;
  float acc[4][8];
#pragma unroll
  for (int p = 0; p < 4; p++)
#pragma unroll
    for (int cc = 0; cc < 8; cc++) acc[p][cc] = 0.0f;
  bool interior = (h0 >= 1) && (h0 + 2 < Hin) && (w0 >= 1) && (w0 + 2 < Win);
  const int rs = Win * Cin;
  for (int ci = 0; ci < Cin; ci++) {
    float patch[4][4];
    if (interior) {
      const float* xp = x + ((b * Hin + (h0 - 1)) * Win + (w0 - 1)) * Cin + ci;
#pragma unroll
      for (int rr = 0; rr < 4; rr++)
#pragma unroll
        for (int cc = 0; cc < 4; cc++)
          patch[rr][cc] = xp[rr * rs + cc * Cin];
    } else {
#pragma unroll
      for (int rr = 0; rr < 4; rr++) {
        int ih = h0 - 1 + rr;
#pragma unroll
        for (int cc = 0; cc < 4; cc++) {
          int iw = w0 - 1 + cc;
          patch[rr][cc] = (ih >= 0 && ih < Hin && iw >= 0 && iw < Win)
                              ? x[((b * Hin + ih) * Win + iw) * Cin + ci] : 0.0f;
        }
      }
    }
#pragma unroll
    for (int ky = 0; ky < 3; ky++) {
#pragma unroll
      for (int kx = 0; kx < 3; kx++) {
        const float* wp = W + (((ky * 3 + kx) * Cin) + ci) * Cout + co;
        float4 wa = *(const float4*)wp;
        float4 wb = *(const float4*)(wp + 4);
        float w8[8] = {wa.x, wa.y, wa.z, wa.w, wb.x, wb.y, wb.z, wb.w};
#pragma unroll
        for (int py = 0; py < 2; py++)
#pragma unroll
          for (int px = 0; px < 2; px++) {
            float iv = patch[py + ky][px + kx];
#pragma unroll
            for (int cc = 0; cc < 8; cc++) acc[py * 2 + px][cc] += iv * w8[cc];
          }
      }
    }
  }
  float* yp = y + ((b * Hout + ph) * Wout + pw) * Cout + co;
#pragma unroll
  for (int cc = 0; cc < 8; cc++) {
    float m = fmaxf(fmaxf(acc[0][cc], acc[1][cc]), fmaxf(acc[2][cc], acc[3][cc]));
    yp[cc] = fmaxf(m + bias[co + cc], 0.0f);
  }
}

// ---------------- conv+relu+pool, 2 pooled outputs per thread --------------
__global__ __launch_bounds__(256) void conv_pool2(
    const float* __restrict__ x, const float* __restrict__ W,
    const float* __restrict__ bias, float* __restrict__ y,
    int Hin, int Win, int Cin, int Cout)
{
  int Hout = Hin >> 1, Wout = Win >> 1, Wq2 = Wout >> 1;
  int cg = Cout >> 3;
  int idx = blockIdx.x * 256 + threadIdx.x;
  int total = 16 * Hout * Wq2 * cg;
  if (idx >= total) return;
  int g = idx % cg; int r = idx / cg;
  int wq = r % Wq2; r /= Wq2;
  int ph = r % Hout; int b = r / Hout;
  int co = g * 8;
  int h0 = ph * 2, w0 = wq * 4;
  float acc[8][8];
#pragma unroll
  for (int p = 0; p < 8; p++)
#pragma unroll
    for (int cc = 0; cc < 8; cc++) acc[p][cc] = 0.0f;
  bool interior = (h0 >= 1) && (h0 + 2 < Hin) && (w0 >= 1) && (w0 + 4 < Win);
  const int rs = Win * Cin;
  for (int ci = 0; ci < Cin; ci++) {
    float patch[4][6];
    if (interior) {
      const float* xp = x + ((b * Hin + (h0 - 1)) * Win + (w0 - 1)) * Cin + ci;
#pragma unroll
      for (int rr = 0; rr < 4; rr++)
#pragma unroll
        for (int cc = 0; cc < 6; cc++)
          patch[rr][cc] = xp[rr * rs + cc * Cin];
    } else {
#pragma unroll
      for (int rr = 0; rr < 4; rr++) {
        int ih = h0 - 1 + rr;
#pragma unroll
        for (int cc = 0; cc < 6; cc++) {
          int iw = w0 - 1 + cc;
          patch[rr][cc] = (ih >= 0 && ih < Hin && iw >= 0 && iw < Win)
                              ? x[((b * Hin + ih) * Win + iw) * Cin + ci] : 0.0f;
        }
      }
    }
#pragma unroll
    for (int ky = 0; ky < 3; ky++) {
#pragma unroll
      for (int kx = 0; kx < 3; kx++) {
        const float* wp = W + (((ky * 3 + kx) * Cin) + ci) * Cout + co;
        float4 wa = *(const float4*)wp;
        float4 wb = *(const float4*)(wp + 4);
        float w8[8] = {wa.x, wa.y, wa.z, wa.w, wb.x, wb.y, wb.z, wb.w};
#pragma unroll
        for (int px0 = 0; px0 < 2; px0++)
#pragma unroll
          for (int py = 0; py < 2; py++)
#pragma unroll
            for (int px = 0; px < 2; px++) {
              float iv = patch[py + ky][px0 * 2 + px + kx];
              int ap = px0 * 4 + py * 2 + px;
#pragma unroll
              for (int cc = 0; cc < 8; cc++) acc[ap][cc] += iv * w8[cc];
            }
      }
    }
  }
#pragma unroll
  for (int px0 = 0; px0 < 2; px0++) {
    float* yp = y + ((b * Hout + ph) * Wout + wq * 2 + px0) * Cout + co;
#pragma unroll
    for (int cc = 0; cc < 8; cc++) {
      float m = fmaxf(fmaxf(acc[px0 * 4 + 0][cc], acc[px0 * 4 + 1][cc]),
                      fmaxf(acc[px0 * 4 + 2][cc], acc[px0 * 4 + 3][cc]));
      yp[cc] = fmaxf(m + bias[co + cc], 0.0f);
    }
  }
}

// ---------------- conv+relu (no pool), 2 pixels per thread -----------------
__global__ __launch_bounds__(256) void conv_nopool2(
    const float* __restrict__ x, const float* __restrict__ W,
    const float* __restrict__ bias, float* __restrict__ y,
    int H, int Wd, int Cin, int Cout)
{
  int Wd2 = Wd >> 1;
  int cg = Cout >> 3;
  int idx = blockIdx.x * 256 + threadIdx.x;
  int total = 16 * H * Wd2 * cg;
  if (idx >= total) return;
  int g = idx % cg; int r = idx / cg;
  int wq = r % Wd2; r /= Wd2;
  int h = r % H; int b = r / H;
  int co = g * 8;
  int w0 = wq * 2;
  float acc[2][8];
#pragma unroll
  for (int p = 0; p < 2; p++)
#pragma unroll
    for (int cc = 0; cc < 8; cc++) acc[p][cc] = 0.0f;
  bool interior = (h >= 1) && (h + 1 < H) && (w0 >= 1) && (w0 + 2 < Wd);
  const int rs = Wd * Cin;
  for (int ci = 0; ci < Cin; ci++) {
    float patch[3][4];
    if (interior) {
      const float* xp = x + ((b * H + (h - 1)) * Wd + (w0 - 1)) * Cin + ci;
#pragma unroll
      for (int rr = 0; rr < 3; rr++)
#pragma unroll
        for (int cc = 0; cc < 4; cc++)
          patch[rr][cc] = xp[rr * rs + cc * Cin];
    } else {
#pragma unroll
      for (int rr = 0; rr < 3; rr++) {
        int ih = h - 1 + rr;
#pragma unroll
        for (int cc = 0; cc < 4; cc++) {
          int iw = w0 - 1 + cc;
          patch[rr][cc] = (ih >= 0 && ih < H && iw >= 0 && iw < Wd)
                              ? x[((b * H + ih) * Wd + iw) * Cin + ci] : 0.0f;
        }
      }
    }
#pragma unroll
    for (int ky = 0; ky < 3; ky++) {
#pragma unroll
      for (int kx = 0; kx < 3; kx++) {
        const float* wp = W + (((ky * 3 + kx) * Cin) + ci) * Cout + co;
        float4 wa = *(const float4*)wp;
        float4 wb = *(const float4*)(wp + 4);
        float w8[8] = {wa.x, wa.y, wa.z, wa.w, wb.x, wb.y, wb.z, wb.w};
#pragma unroll
        for (int px = 0; px < 2; px++) {
          float iv = patch[ky][px + kx];
#pragma unroll
          for (int cc = 0; cc < 8; cc++) acc[px][cc] += iv * w8[cc];
        }
      }
    }
  }
#pragma unroll
  for (int px = 0; px < 2; px++) {
    float* yp = y + ((b * H + h) * Wd + w0 + px) * Cout + co;
#pragma unroll
    for (int cc = 0; cc < 8; cc++)
      yp[cc] = fmaxf(acc[px][cc] + bias[co + cc], 0.0f);
  }
}

// ---------------- 128x128 tiled SGEMM, 8x8 per thread ----------------------
__global__ __launch_bounds__(256) void sgemm128(
    const float* __restrict__ A, int lda,
    const float* __restrict__ Bm, int ldb,
    void* __restrict__ C, int ldc,
    const float* __restrict__ bias,
    const float* __restrict__ Dadd, int ldd,
    int M, int N, int K, int amode, int cmode,
    const int* __restrict__ labels, const float* __restrict__ emb)
{
  __shared__ float As[8][132];
  __shared__ float Bs[8][132];
  int tid = threadIdx.x;
  int m0 = blockIdx.y * 128, n0 = blockIdx.x * 128;
  int tx = tid & 15, ty = tid >> 4;
  float acc[8][8];
#pragma unroll
  for (int i = 0; i < 8; i++)
#pragma unroll
    for (int j = 0; j < 8; j++) acc[i][j] = 0.0f;
  int arow = tid >> 1, ak = (tid & 1) * 4;
  int bkr = tid >> 5, bn = (tid & 31) * 4;
  for (int k0 = 0; k0 < K; k0 += 8) {
    float4 av = make_float4(0.f, 0.f, 0.f, 0.f);
    int row = m0 + arow;
    if (row < M) {
      const float* ap;
      if (amode == 0) {
        ap = A + (size_t)row * lda + k0 + ak;
      } else {
        int t = row >> 4, b = row & 15;
        ap = emb + labels[b * TLAB + t] * 80 + k0 + ak;
      }
      av = *(const float4*)ap;
    }
    As[ak + 0][arow] = av.x; As[ak + 1][arow] = av.y;
    As[ak + 2][arow] = av.z; As[ak + 3][arow] = av.w;
    {
      float4 bv = make_float4(0.f, 0.f, 0.f, 0.f);
      int col = n0 + bn;
      const float* bp = Bm + (size_t)(k0 + bkr) * ldb + col;
      if (col + 3 < N) {
        bv = *(const float4*)bp;
      } else if (col < N) {
        bv.x = bp[0];
        if (col + 1 < N) bv.y = bp[1];
        if (col + 2 < N) bv.z = bp[2];
      }
      *(float4*)&Bs[bkr][bn] = bv;
    }
    __syncthreads();
#pragma unroll
    for (int kk = 0; kk < 8; kk++) {
      float a[8], b[8];
      *(float4*)&a[0] = *(const float4*)&As[kk][ty * 8];
      *(float4*)&a[4] = *(const float4*)&As[kk][ty * 8 + 4];
      *(float4*)&b[0] = *(const float4*)&Bs[kk][tx * 8];
      *(float4*)&b[4] = *(const float4*)&Bs[kk][tx * 8 + 4];
#pragma unroll
      for (int i = 0; i < 8; i++)
#pragma unroll
        for (int j = 0; j < 8; j++) acc[i][j] += a[i] * b[j];
    }
    __syncthreads();
  }
#pragma unroll
  for (int i = 0; i < 8; i++) {
    int row = m0 + ty * 8 + i;
    if (row >= M) continue;
#pragma unroll
    for (int j = 0; j < 8; j++) {
      int col = n0 + tx * 8 + j;
      if (col >= N) continue;
      float v = acc[i][j];
      if (Dadd) v += Dadd[(size_t)row * ldd + col];
      if (bias) v += bias[col];
      if (cmode == 0) {
        ((float*)C)[(size_t)row * ldc + col] = v;
      } else if (cmode == 1) {
        int t = row >> 4, b2 = row & 15;
        ((float*)C)[((size_t)b2 * TDEC + t) * 504 + col] = v;
      } else if (cmode == 2) {
        ((float*)C)[(size_t)col * ldc + row] = v;
      } else if (cmode == 3) {
        unsigned bits = __float_as_uint(v);
        u16 h = (u16)((bits + 0x8000u) >> 16);
        ((u16*)C)[(size_t)row * ldc + col] = h;
      } else { // cmode 4
        int b2 = row >> 9, l = row & 511;
        unsigned bits = __float_as_uint(v);
        u16 h = (u16)((bits + 0x8000u) >> 16);
        ((u16*)C)[((size_t)(b2 * 512 + col)) * 512 + l] = h;
      }
    }
  }
}

// ---------------- 32x32 tiled transpose ------------------------------------
__global__ __launch_bounds__(256) void transpose32(
    const float* __restrict__ src, int lds_, int M, int N,
    float* __restrict__ dst, int ldd_, int off)
{
  __shared__ float tle[32][33];
  int tid = threadIdx.x;
  int x = tid & 31, y8 = tid >> 5;
  int m0 = blockIdx.y * 32, n0 = blockIdx.x * 32;
#pragma unroll
  for (int p = 0; p < 4; p++) {
    int m = m0 + y8 + p * 8, n = n0 + x;
    if (m < M && n < N) tle[y8 + p * 8][x] = src[(size_t)m * lds_ + n];
  }
  __syncthreads();
#pragma unroll
  for (int p = 0; p < 4; p++) {
    int n = n0 + y8 + p * 8, m = m0 + x;
    if (n < N && m < M) dst[(size_t)n * ldd_ + off + m] = tle[x][y8 + p * 8];
  }
}

// ---------------- persistent encoder: all 64 steps, one dispatch -----------
// h0 == 0 handled analytically (t==0 skips the h@Wh matvec) — henc[0] is
// NEVER read, so no init needed (fixes the c3-aliasing clobber of round 5).
__global__ __launch_bounds__(256) void enc_persist(
    const float* __restrict__ Zfw, const float* __restrict__ Zbw,
    const float* __restrict__ Whfw, const float* __restrict__ Whbw,
    float* __restrict__ henc, float* __restrict__ mem,
    unsigned* __restrict__ earr)
{
  __shared__ float WL[16][260];
  __shared__ float hsh[128][130];
  __shared__ float zl[128][17];
  int tid = threadIdx.x;
  int bi = blockIdx.x;
  int dir = bi >> 6, u0 = (bi & 63) * 4;
  const float* Wh = dir ? Whbw : Whfw;
  const float* Z = dir ? Zbw : Zfw;
  {
    const float* src = Wh + (size_t)tid * 1024 + u0;
#pragma unroll
    for (int g = 0; g < 4; g++) {
      float4 w4 = *(const float4*)(src + g * 256);
      WL[g * 4 + 0][tid] = w4.x; WL[g * 4 + 1][tid] = w4.y;
      WL[g * 4 + 2][tid] = w4.z; WL[g * 4 + 3][tid] = w4.w;
    }
  }
  float creg[2] = {0.0f, 0.0f};
  __syncthreads();

  int c2 = tid & 7, q = tid >> 3;
  for (int t = 0; t < 64; t++) {
    int wp = dir ? (63 - t) : t;
    float a0[4], a1[4];
#pragma unroll
    for (int i = 0; i < 4; i++) { a0[i] = 0.f; a1[i] = 0.f; }
    if (t > 0) {
      const float* hsrc = henc + (size_t)t * 65536 + dir * 32768;
#pragma unroll
      for (int half = 0; half < 2; half++) {
        __syncthreads();
#pragma unroll
        for (int i = 0; i < 16; i++) {
          int flat = i * 256 + tid;
          int n = flat >> 5, kq = flat & 31;
          *(float4*)&hsh[n][kq * 4] = *(const float4*)&hsrc[n * 256 + half * 128 + kq * 4];
        }
        __syncthreads();
        int kw = half * 128;
        for (int k4 = 0; k4 < 32; k4++) {
          float4 w0 = *(const float4*)&WL[c2 * 2 + 0][kw + k4 * 4];
          float4 w1 = *(const float4*)&WL[c2 * 2 + 1][kw + k4 * 4];
#pragma unroll
          for (int i = 0; i < 4; i++) {
            float4 h4 = *(const float4*)&hsh[q * 4 + i][k4 * 4];
            a0[i] += h4.x * w0.x + h4.y * w0.y + h4.z * w0.z + h4.w * w0.w;
            a1[i] += h4.x * w1.x + h4.y * w1.y + h4.z * w1.z + h4.w * w1.w;
          }
        }
      }
    }
#pragma unroll
    for (int i = 0; i < 4; i++) {
      zl[q * 4 + i][c2 * 2 + 0] = a0[i];
      zl[q * 4 + i][c2 * 2 + 1] = a1[i];
    }
    __syncthreads();
#pragma unroll
    for (int s2 = 0; s2 < 2; s2++) {
      int s = tid + s2 * 256;
      int n = s >> 2, uj = s & 3;
      int u = u0 + uj;
      size_t zoff = ((size_t)(n * 64 + wp)) * 1024 + u;
      float zi = zl[n][0 + uj] + Z[zoff];
      float zj = zl[n][4 + uj] + Z[zoff + 256];
      float zf = zl[n][8 + uj] + Z[zoff + 512];
      float zo = zl[n][12 + uj] + Z[zoff + 768];
      float cn = sigm(zf + 1.0f) * creg[s2] + sigm(zi) * tanhfast(zj);
      float hn = sigm(zo) * tanhfast(cn);
      creg[s2] = cn;
      if (t < 63)
        stf_cg(&henc[(size_t)(t + 1) * 65536 + dir * 32768 + n * 256 + u], hn);
      int b = n >> 3, hp = n & 7;
      mem[((size_t)(b * 512 + hp * 64 + wp)) * 512 + dir * 256 + u] = hn;
    }
    if (t < 63) {
      asm volatile("s_waitcnt vmcnt(0)" ::: "memory");
      __syncthreads();
      unsigned ep = t + 1;
      if (tid == 0) st_cg(&earr[bi * 32], ep);
      if (tid < 128)
        while (ld_cg(&earr[tid * 32]) < ep) __builtin_amdgcn_s_sleep(2);
      __syncthreads();
      acq_fence();
    }
  }
}

// ---------------- persistent decoder barriers ------------------------------
__device__ __forceinline__ void bar_full(unsigned* arr, unsigned ep) {
  asm volatile("s_waitcnt vmcnt(0)" ::: "memory");
  __syncthreads();
  if (threadIdx.x == 0) st_cg(&arr[blockIdx.x * 32], ep);
  while (ld_cg(&arr[threadIdx.x * 32]) < ep) __builtin_amdgcn_s_sleep(2);
  __syncthreads();
  acq_fence();
}
__device__ __forceinline__ void bar_grp(unsigned* arr, int g, unsigned ep) {
  asm volatile("s_waitcnt vmcnt(0)" ::: "memory");
  __syncthreads();
  int tid = threadIdx.x;
  if (tid == 0) st_cg(&arr[blockIdx.x * 32], ep);
  if (tid < 16) {
    int peer = (g & 7) + ((g >> 3) << 7) + (tid << 3);
    while (ld_cg(&arr[peer * 32]) < ep) __builtin_amdgcn_s_sleep(2);
  }
  __syncthreads();
  acq_fence();
}

// ---------------- persistent decoder: all 150 steps in one dispatch --------
__global__ __launch_bounds__(256) void dec_persist(
    const float* __restrict__ WcatT, const float* __restrict__ Zemb,
    const float* __restrict__ WqT, const u16* __restrict__ keysB,
    const u16* __restrict__ memBT, const float* __restrict__ vatt,
    float* __restrict__ hist, float* __restrict__ qbuf_t,
    float* __restrict__ scor_t, unsigned* __restrict__ arr)
{
  __shared__ float hl[16][516];   // staged [h|ctx] half: 16 b x 512
  __shared__ float WT[8][1036];   // fp32 Wcat slice: 8 cols x 1024 k
  __shared__ float vbs[512];
  __shared__ float ez[512];
  __shared__ float redw[4];
  __shared__ float zl[16][8];
  __shared__ float cstL[16][2];
  int tid = threadIdx.x;
  int bi = blockIdx.x;
  int bq = (bi & 7) + 8 * (bi >> 7);   // batch group on XCD (bq&7)
  int chunk = (bi >> 3) & 15;

  {
    int c = tid >> 5, lt = tid & 31;
    int u = bi * 2 + (c & 1), g = c >> 1;
    const float* srcw = WcatT + ((size_t)(g * 512 + u)) * 1024;
#pragma unroll
    for (int i = 0; i < 8; i++) {
      int k = i * 128 + lt * 4;
      *(float4*)&WT[c][k] = *(const float4*)&srcw[k];
    }
  }
  if (tid < 128) {
    float4 v4 = ((const float4*)vatt)[tid];
    int d = tid * 4;
    vbs[EZX(d + 0)] = v4.x; vbs[EZX(d + 1)] = v4.y;
    vbs[EZX(d + 2)] = v4.z; vbs[EZX(d + 3)] = v4.w;
  }
  if (tid < 32) cstL[tid >> 1][tid & 1] = 0.0f;
  __syncthreads();

  for (int t = 0; t < TDEC; t++) {
    // ---- CELL ----
    {
      float acc = 0.0f;
      int b = tid >> 4, c = (tid >> 1) & 7, ks = tid & 1;
      if (t > 0) {
        const float* hp = hist + (size_t)(t - 1) * 16384;
#pragma unroll
        for (int half = 0; half < 2; half++) {
          __syncthreads();
#pragma unroll
          for (int it = 0; it < 8; it++) {
            int f4 = it * 256 + tid;
            int sb = f4 >> 7, si = (f4 & 127) * 4;
            *(float4*)&hl[sb][si] = *(const float4*)&hp[sb * 1024 + half * 512 + si];
          }
          __syncthreads();
          const float* wrow = &WT[c][half * 512 + ks * 256];
          const float* hrow = &hl[b][ks * 256];
#pragma unroll 8
          for (int i = 0; i < 64; i++) {
            float4 w4 = *(const float4*)&wrow[i * 4];
            float4 h4 = *(const float4*)&hrow[i * 4];
            acc += w4.x * h4.x + w4.y * h4.y + w4.z * h4.z + w4.w * h4.w;
          }
        }
      }
      acc += __shfl_xor(acc, 1, 64);
      if (ks == 0) {
        int u = bi * 2 + (c & 1), g = c >> 1;
        zl[b][c] = acc + Zemb[(size_t)(t * 16 + b) * 2048 + g * 512 + u];
      }
    }
    __syncthreads();
    if (tid < 32) {
      int b = tid >> 1, uu = tid & 1;
      float zi = zl[b][uu], zj = zl[b][2 + uu], zf = zl[b][4 + uu], zo = zl[b][6 + uu];
      float cold = cstL[b][uu];
      float cn = sigm(zf + 1.0f) * cold + sigm(zi) * tanhfast(zj);
      float hn = sigm(zo) * tanhfast(cn);
      cstL[b][uu] = cn;
      stf_cg(&hist[(size_t)t * 16384 + b * 1024 + bi * 2 + uu], hn);
    }
    bar_full(arr, 4 * t + 1);

    // ---- Q ----
    {
      int jl = tid >> 3, ks = tid & 7;
      int j = chunk * 32 + jl;
      const float* wr = WqT + (size_t)j * 512 + ks * 64;
      const float* hr = hist + (size_t)t * 16384 + bq * 1024 + ks * 64;
      float acc = 0.f;
#pragma unroll
      for (int i = 0; i < 16; i++) {
        float4 w4 = *(const float4*)&wr[i * 4];
        float4 h4 = *(const float4*)&hr[i * 4];
        acc += w4.x * h4.x + w4.y * h4.y + w4.z * h4.z + w4.w * h4.w;
      }
      acc += __shfl_xor(acc, 1, 64);
      acc += __shfl_xor(acc, 2, 64);
      acc += __shfl_xor(acc, 4, 64);
      if (ks == 0) stf_cg(&qbuf_t[(size_t)t * 8192 + bq * 512 + j], acc);
    }
    bar_grp(arr, bq, 4 * t + 2);

    // ---- SCORE ----
    {
      int l = chunk * 32 + (tid >> 3), dk = tid & 7;
      const u16* kp = keysB + ((size_t)(bq * 512 + l)) * 512 + dk * 64;
      const float* qp = qbuf_t + (size_t)t * 8192 + bq * 512 + dk * 64;
      float acc = 0.f;
#pragma unroll
      for (int i = 0; i < 8; i++) {
        uint4 kv = *(const uint4*)(kp + i * 8);
        float4 qa = *(const float4*)(qp + i * 8);
        float4 qb = *(const float4*)(qp + i * 8 + 4);
        int base = i * 64 + dk;
        acc += vbs[base +  0] * tanhfast(bflo(kv.x) + qa.x);
        acc += vbs[base +  8] * tanhfast(bfhi(kv.x) + qa.y);
        acc += vbs[base + 16] * tanhfast(bflo(kv.y) + qa.z);
        acc += vbs[base + 24] * tanhfast(bfhi(kv.y) + qa.w);
        acc += vbs[base + 32] * tanhfast(bflo(kv.z) + qb.x);
        acc += vbs[base + 40] * tanhfast(bfhi(kv.z) + qb.y);
        acc += vbs[base + 48] * tanhfast(bflo(kv.w) + qb.z);
        acc += vbs[base + 56] * tanhfast(bfhi(kv.w) + qb.w);
      }
      acc += __shfl_xor(acc, 1, 64);
      acc += __shfl_xor(acc, 2, 64);
      acc += __shfl_xor(acc, 4, 64);
      if (dk == 0) stf_cg(&scor_t[(size_t)t * 8192 + bq * 512 + l], acc);
    }
    bar_grp(arr, bq, 4 * t + 3);

    // ---- CTX ----
    {
      float2 sv = *(const float2*)&scor_t[(size_t)t * 8192 + bq * 512 + tid * 2];
      float e0 = __expf(sv.x), e1 = __expf(sv.y);
      ez[EZX(tid * 2)] = e0; ez[EZX(tid * 2 + 1)] = e1;
      float s = e0 + e1;
#pragma unroll
      for (int d = 1; d < 64; d <<= 1) s += __shfl_xor(s, d, 64);
      if ((tid & 63) == 0) redw[tid >> 6] = s;
      __syncthreads();
      float den = redw[0] + redw[1] + redw[2] + redw[3];
      int jl = tid >> 3, ls = tid & 7;
      int j = chunk * 32 + jl;
      const u16* mp = memBT + ((size_t)(bq * 512 + j)) * 512 + ls * 64;
      float acc = 0.f;
#pragma unroll
      for (int i = 0; i < 8; i++) {
        uint4 mv = *(const uint4*)(mp + i * 8);
        int base = i * 64 + ls;
        acc += ez[base +  0] * bflo(mv.x);
        acc += ez[base +  8] * bfhi(mv.x);
        acc += ez[base + 16] * bflo(mv.y);
        acc += ez[base + 24] * bfhi(mv.y);
        acc += ez[base + 32] * bflo(mv.z);
        acc += ez[base + 40] * bfhi(mv.z);
        acc += ez[base + 48] * bflo(mv.w);
        acc += ez[base + 56] * bfhi(mv.w);
      }
      acc += __shfl_xor(acc, 1, 64);
      acc += __shfl_xor(acc, 2, 64);
      acc += __shfl_xor(acc, 4, 64);
      if (ls == 0)
        stf_cg(&hist[(size_t)t * 16384 + bq * 1024 + 512 + j], acc / den);
    }
    if (t < TDEC - 1) bar_full(arr, 4 * t + 4);
  }
}

// ---------------------------------------------------------------------------
extern "C" void kernel_launch(void* const* d_in, const int* in_sizes, int n_in,
                              void* d_out, int out_size, void* d_ws, size_t ws_size,
                              hipStream_t stream) {
  (void)in_sizes; (void)n_in; (void)out_size; (void)ws_size;
  const float* inp   = (const float*)d_in[0];
  const int*   labels= (const int*)  d_in[1];
  const float* ck1 = (const float*)d_in[3];
  const float* cb1 = (const float*)d_in[4];
  const float* ck2 = (const float*)d_in[5];
  const float* cb2 = (const float*)d_in[6];
  const float* ck3 = (const float*)d_in[7];
  const float* cb3 = (const float*)d_in[8];
  const float* ck4 = (const float*)d_in[9];
  const float* cb4 = (const float*)d_in[10];
  const float* Wfw = (const float*)d_in[11];
  const float* bfw = (const float*)d_in[12];
  const float* Wbw = (const float*)d_in[13];
  const float* bbw = (const float*)d_in[14];
  const float* Wdec= (const float*)d_in[15];
  const float* bdec= (const float*)d_in[16];
  const float* Wmem= (const float*)d_in[17];
  const float* Wq  = (const float*)d_in[18];
  const float* vatt= (const float*)d_in[19];
  const float* Wattn=(const float*)d_in[20];
  const float* Wout= (const float*)d_in[21];
  const float* bout= (const float*)d_in[22];
  const float* emb = (const float*)d_in[23];
  float* out = (float*)d_out;
  float* ws  = (float*)d_ws;

  // workspace layout (float slots)
  const size_t OFF_P1    = 0;           // p1 / Zfw / Zemb
  const size_t OFF_ZBW   = 8388608;     // p2 / Zbw; decoder-time: qbuf_t/scor_t
  const size_t OFF_QT    = 8388608;
  const size_t OFF_ST    = 9617408;
  const size_t OFF_C3    = 12582912;    // c3 spans [12582912, 20971520)
  const size_t OFF_HIST  = 16777216;    // inside dead c3; henc[0] never read
  const size_t OFF_P4    = 20971520;
  const size_t OFF_MEM   = 25165824;
  const size_t OFF_KEYSB = 29360128;
  const size_t OFF_MEMBT = 31457280;
  const size_t OFF_WCATT = 33554432;
  const size_t OFF_WQT   = 35651584;
  const size_t OFF_WCAT2 = 35913728;
  const size_t OFF_ARR   = 36429824;    // 8192 u32 (dec barrier)
  const size_t OFF_EARR  = 36438016;    // 4096 u32 (enc barrier)

  float* p1    = ws + OFF_P1;
  float* p2    = ws + OFF_ZBW;
  float* c3    = ws + OFF_C3;
  float* p4    = ws + OFF_P4;
  float* Zfw   = ws + OFF_P1;
  float* Zbw   = ws + OFF_ZBW;
  float* Zemb  = ws + OFF_P1;
  float* qbuf_t= ws + OFF_QT;
  float* scor_t= ws + OFF_ST;
  float* hist  = ws + OFF_HIST;
  float* henc  = ws + OFF_HIST;
  float* memv  = ws + OFF_MEM;
  u16*   keysB = (u16*)(ws + OFF_KEYSB);
  u16*   memBT = (u16*)(ws + OFF_MEMBT);
  float* WcatT = ws + OFF_WCATT;
  float* WqT   = ws + OFF_WQT;
  float* Wcat2 = ws + OFF_WCAT2;
  unsigned* arr  = (unsigned*)(ws + OFF_ARR);
  unsigned* earr = (unsigned*)(ws + OFF_EARR);

  hipMemsetAsync(arr, 0, (8192 + 4096) * 4, stream);   // arr + earr contiguous

  // CNN
  conv_pool   <<<4096, 256, 0, stream>>>(inp, ck1, cb1, p1, 64, 512, 1, 64);
  conv_pool2  <<<1024, 256, 0, stream>>>(p1, ck2, cb2, p2, 32, 256, 64, 128);
  conv_nopool2<<<2048, 256, 0, stream>>>(p2, ck3, cb3, c3, 16, 128, 128, 256);
  conv_pool2  <<<1024, 256, 0, stream>>>(c3, ck4, cb4, p4, 16, 128, 256, 512);

  // encoder input-side GEMMs
  sgemm128<<<dim3(8, 64), 256, 0, stream>>>(p4, 512, Wfw, 1024, Zfw, 1024, bfw,
                                            nullptr, 0, 8192, 1024, 512, 0, 0, nullptr, nullptr);
  sgemm128<<<dim3(8, 64), 256, 0, stream>>>(p4, 512, Wbw, 1024, Zbw, 1024, bbw,
                                            nullptr, 0, 8192, 1024, 512, 0, 0, nullptr, nullptr);
  // encoder recurrence: one persistent dispatch
  enc_persist<<<128, 256, 0, stream>>>(Zfw, Zbw, Wfw + 512 * 1024, Wbw + 512 * 1024,
                                       henc, memv, earr);

  // attention precomputes (bf16 outputs for decoder streaming)
  sgemm128<<<dim3(4, 64), 256, 0, stream>>>(memv, 512, Wmem, 512, keysB, 512,
                                            nullptr, nullptr, 0, 8192, 512, 512, 0, 3, nullptr, nullptr);
  sgemm128<<<dim3(4, 64), 256, 0, stream>>>(memv, 512, Wattn + 512 * 512, 512, memBT, 512,
                                            nullptr, nullptr, 0, 8192, 512, 512, 0, 4, nullptr, nullptr);
  // WcatT upper: (W1@Wdec_a + Wdec_h)^T
  sgemm128<<<dim3(16, 4), 256, 0, stream>>>(Wattn, 512, Wdec + 80 * 2048, 2048, WcatT, 1024,
                                            nullptr, Wdec + 592 * 2048, 2048,
                                            512, 2048, 512, 0, 2, nullptr, nullptr);
  // WcatT lower: Wdec_a^T
  transpose32<<<dim3(64, 16), 256, 0, stream>>>(Wdec + 80 * 2048, 2048, 512, 2048, WcatT, 1024, 512);
  // WqT
  transpose32<<<dim3(16, 16), 256, 0, stream>>>(Wq, 512, 512, 512, WqT, 512, 0);
  // Wcat2
  sgemm128<<<dim3(4, 4), 256, 0, stream>>>(Wattn, 512, Wout, 504, Wcat2, 504,
                                           nullptr, nullptr, 0, 512, 504, 512, 0, 0, nullptr, nullptr);
  hipMemcpyAsync(Wcat2 + 512 * 504, Wout, (size_t)512 * 504 * 4, hipMemcpyDeviceToDevice, stream);
  // Zemb
  sgemm128<<<dim3(16, 19), 256, 0, stream>>>(nullptr, 0, Wdec, 2048, Zemb, 2048, bdec,
                                             nullptr, 0, 2400, 2048, 80, 1, 0, labels, emb);

  // decoder: one persistent dispatch
  dec_persist<<<256, 256, 0, stream>>>(WcatT, Zemb, WqT, keysB, memBT, vatt,
                                       hist, qbuf_t, scor_t, arr);

  // logits
  sgemm128<<<dim3(4, 19), 256, 0, stream>>>(hist, 1024, Wcat2, 504, out, 504, bout,
                                            nullptr, 0, 2400, 504, 1024, 0, 1, nullptr, nullptr);
}

// Round 8
// 8147.720 us; speedup vs baseline: 1.5418x; 1.5418x over previous
//
#include <hip/hip_runtime.h>
#include <cstddef>

// ---------------------------------------------------------------------------
// TrainModel: CNN -> BiLSTM encoder -> attention decoder.
// B=16, image 64x512x1, Hp=8, Wp=64, ENC_H=256, DEC_H=512, ATT=512, VOCAB=504
// Round 8: round 7 minus agent-scope acquire fences.  On gfx950 the agent
// acquire lowers to an L2-wide invalidate (8 XCDs, per-XCD L2) -> 600
// barriers thrashed L2 for all CUs (FETCH 151->257MB, 48ms outliers).
// Write-once payloads + spin barriers were empirically correct without
// fences (rounds 3/4); round 5/6 failure was the henc[0]/c3 aliasing bug.
// ---------------------------------------------------------------------------

#define TDEC 150
#define TLAB 151
typedef unsigned short u16;

__device__ __forceinline__ float sigm(float x) { return 1.0f / (1.0f + __expf(-x)); }
__device__ __forceinline__ float tanhfast(float x) {
  float ax = fabsf(x);
  float e = __expf(-2.0f * ax);
  float t = (1.0f - e) / (1.0f + e);
  return x < 0.0f ? -t : t;
}
__device__ __forceinline__ int EZX(int d) { return ((d & 63) << 3) | (d >> 6); }

__device__ __forceinline__ unsigned ld_cg(const unsigned* p) {
  return __hip_atomic_load(p, __ATOMIC_RELAXED, __HIP_MEMORY_SCOPE_AGENT);
}
__device__ __forceinline__ void st_cg(unsigned* p, unsigned v) {
  __hip_atomic_store(p, v, __ATOMIC_RELAXED, __HIP_MEMORY_SCOPE_AGENT);
}
__device__ __forceinline__ void stf_cg(float* p, float v) {
  __hip_atomic_store(p, v, __ATOMIC_RELAXED, __HIP_MEMORY_SCOPE_AGENT);
}
__device__ __forceinline__ float bfhi(unsigned x) { return __uint_as_float(x & 0xFFFF0000u); }
__device__ __forceinline__ float bflo(unsigned x) { return __uint_as_float(x << 16); }

// ---------------- conv1: fused conv3x3 + relu + pool -----------------------
__global__ __launch_bounds__(256) void conv_pool(
    const float* __restrict__ x, const float* __restrict__ W,
    const float* __restrict__ bias, float* __restrict__ y,
    int Hin, int Win, int Cin, int Cout)
{
  int Hout = Hin >> 1, Wout = Win >> 1;
  int cg = Cout >> 3;
  int idx = blockIdx.x * 256 + threadIdx.x;
  int total = 16 * Hout * Wout * cg;
  if (idx >= total) return;
  int g = idx % cg; int r = idx / cg;
  int pw = r % Wout; r /= Wout;
  int ph = r % Hout; int b = r / Hout;
  int co = g * 8;
  int h0 = ph * 2, w0 = pw * 2;
  float acc[4][8];
#pragma unroll
  for (int p = 0; p < 4; p++)
#pragma unroll
    for (int cc = 0; cc < 8; cc++) acc[p][cc] = 0.0f;
  bool interior = (h0 >= 1) && (h0 + 2 < Hin) && (w0 >= 1) && (w0 + 2 < Win);
  const int rs = Win * Cin;
  for (int ci = 0; ci < Cin; ci++) {
    float patch[4][4];
    if (interior) {
      const float* xp = x + ((b * Hin + (h0 - 1)) * Win + (w0 - 1)) * Cin + ci;
#pragma unroll
      for (int rr = 0; rr < 4; rr++)
#pragma unroll
        for (int cc = 0; cc < 4; cc++)
          patch[rr][cc] = xp[rr * rs + cc * Cin];
    } else {
#pragma unroll
      for (int rr = 0; rr < 4; rr++) {
        int ih = h0 - 1 + rr;
#pragma unroll
        for (int cc = 0; cc < 4; cc++) {
          int iw = w0 - 1 + cc;
          patch[rr][cc] = (ih >= 0 && ih < Hin && iw >= 0 && iw < Win)
                              ? x[((b * Hin + ih) * Win + iw) * Cin + ci] : 0.0f;
        }
      }
    }
#pragma unroll
    for (int ky = 0; ky < 3; ky++) {
#pragma unroll
      for (int kx = 0; kx < 3; kx++) {
        const float* wp = W + (((ky * 3 + kx) * Cin) + ci) * Cout + co;
        float4 wa = *(const float4*)wp;
        float4 wb = *(const float4*)(wp + 4);
        float w8[8] = {wa.x, wa.y, wa.z, wa.w, wb.x, wb.y, wb.z, wb.w};
#pragma unroll
        for (int py = 0; py < 2; py++)
#pragma unroll
          for (int px = 0; px < 2; px++) {
            float iv = patch[py + ky][px + kx];
#pragma unroll
            for (int cc = 0; cc < 8; cc++) acc[py * 2 + px][cc] += iv * w8[cc];
          }
      }
    }
  }
  float* yp = y + ((b * Hout + ph) * Wout + pw) * Cout + co;
#pragma unroll
  for (int cc = 0; cc < 8; cc++) {
    float m = fmaxf(fmaxf(acc[0][cc], acc[1][cc]), fmaxf(acc[2][cc], acc[3][cc]));
    yp[cc] = fmaxf(m + bias[co + cc], 0.0f);
  }
}

// ---------------- conv+relu+pool, 2 pooled outputs per thread --------------
__global__ __launch_bounds__(256) void conv_pool2(
    const float* __restrict__ x, const float* __restrict__ W,
    const float* __restrict__ bias, float* __restrict__ y,
    int Hin, int Win, int Cin, int Cout)
{
  int Hout = Hin >> 1, Wout = Win >> 1, Wq2 = Wout >> 1;
  int cg = Cout >> 3;
  int idx = blockIdx.x * 256 + threadIdx.x;
  int total = 16 * Hout * Wq2 * cg;
  if (idx >= total) return;
  int g = idx % cg; int r = idx / cg;
  int wq = r % Wq2; r /= Wq2;
  int ph = r % Hout; int b = r / Hout;
  int co = g * 8;
  int h0 = ph * 2, w0 = wq * 4;
  float acc[8][8];
#pragma unroll
  for (int p = 0; p < 8; p++)
#pragma unroll
    for (int cc = 0; cc < 8; cc++) acc[p][cc] = 0.0f;
  bool interior = (h0 >= 1) && (h0 + 2 < Hin) && (w0 >= 1) && (w0 + 4 < Win);
  const int rs = Win * Cin;
  for (int ci = 0; ci < Cin; ci++) {
    float patch[4][6];
    if (interior) {
      const float* xp = x + ((b * Hin + (h0 - 1)) * Win + (w0 - 1)) * Cin + ci;
#pragma unroll
      for (int rr = 0; rr < 4; rr++)
#pragma unroll
        for (int cc = 0; cc < 6; cc++)
          patch[rr][cc] = xp[rr * rs + cc * Cin];
    } else {
#pragma unroll
      for (int rr = 0; rr < 4; rr++) {
        int ih = h0 - 1 + rr;
#pragma unroll
        for (int cc = 0; cc < 6; cc++) {
          int iw = w0 - 1 + cc;
          patch[rr][cc] = (ih >= 0 && ih < Hin && iw >= 0 && iw < Win)
                              ? x[((b * Hin + ih) * Win + iw) * Cin + ci] : 0.0f;
        }
      }
    }
#pragma unroll
    for (int ky = 0; ky < 3; ky++) {
#pragma unroll
      for (int kx = 0; kx < 3; kx++) {
        const float* wp = W + (((ky * 3 + kx) * Cin) + ci) * Cout + co;
        float4 wa = *(const float4*)wp;
        float4 wb = *(const float4*)(wp + 4);
        float w8[8] = {wa.x, wa.y, wa.z, wa.w, wb.x, wb.y, wb.z, wb.w};
#pragma unroll
        for (int px0 = 0; px0 < 2; px0++)
#pragma unroll
          for (int py = 0; py < 2; py++)
#pragma unroll
            for (int px = 0; px < 2; px++) {
              float iv = patch[py + ky][px0 * 2 + px + kx];
              int ap = px0 * 4 + py * 2 + px;
#pragma unroll
              for (int cc = 0; cc < 8; cc++) acc[ap][cc] += iv * w8[cc];
            }
      }
    }
  }
#pragma unroll
  for (int px0 = 0; px0 < 2; px0++) {
    float* yp = y + ((b * Hout + ph) * Wout + wq * 2 + px0) * Cout + co;
#pragma unroll
    for (int cc = 0; cc < 8; cc++) {
      float m = fmaxf(fmaxf(acc[px0 * 4 + 0][cc], acc[px0 * 4 + 1][cc]),
                      fmaxf(acc[px0 * 4 + 2][cc], acc[px0 * 4 + 3][cc]));
      yp[cc] = fmaxf(m + bias[co + cc], 0.0f);
    }
  }
}

// ---------------- conv+relu (no pool), 2 pixels per thread -----------------
__global__ __launch_bounds__(256) void conv_nopool2(
    const float* __restrict__ x, const float* __restrict__ W,
    const float* __restrict__ bias, float* __restrict__ y,
    int H, int Wd, int Cin, int Cout)
{
  int Wd2 = Wd >> 1;
  int cg = Cout >> 3;
  int idx = blockIdx.x * 256 + threadIdx.x;
  int total = 16 * H * Wd2 * cg;
  if (idx >= total) return;
  int g = idx % cg; int r = idx / cg;
  int wq = r % Wd2; r /= Wd2;
  int h = r % H; int b = r / H;
  int co = g * 8;
  int w0 = wq * 2;
  float acc[2][8];
#pragma unroll
  for (int p = 0; p < 2; p++)
#pragma unroll
    for (int cc = 0; cc < 8; cc++) acc[p][cc] = 0.0f;
  bool interior = (h >= 1) && (h + 1 < H) && (w0 >= 1) && (w0 + 2 < Wd);
  const int rs = Wd * Cin;
  for (int ci = 0; ci < Cin; ci++) {
    float patch[3][4];
    if (interior) {
      const float* xp = x + ((b * H + (h - 1)) * Wd + (w0 - 1)) * Cin + ci;
#pragma unroll
      for (int rr = 0; rr < 3; rr++)
#pragma unroll
        for (int cc = 0; cc < 4; cc++)
          patch[rr][cc] = xp[rr * rs + cc * Cin];
    } else {
#pragma unroll
      for (int rr = 0; rr < 3; rr++) {
        int ih = h - 1 + rr;
#pragma unroll
        for (int cc = 0; cc < 4; cc++) {
          int iw = w0 - 1 + cc;
          patch[rr][cc] = (ih >= 0 && ih < H && iw >= 0 && iw < Wd)
                              ? x[((b * H + ih) * Wd + iw) * Cin + ci] : 0.0f;
        }
      }
    }
#pragma unroll
    for (int ky = 0; ky < 3; ky++) {
#pragma unroll
      for (int kx = 0; kx < 3; kx++) {
        const float* wp = W + (((ky * 3 + kx) * Cin) + ci) * Cout + co;
        float4 wa = *(const float4*)wp;
        float4 wb = *(const float4*)(wp + 4);
        float w8[8] = {wa.x, wa.y, wa.z, wa.w, wb.x, wb.y, wb.z, wb.w};
#pragma unroll
        for (int px = 0; px < 2; px++) {
          float iv = patch[ky][px + kx];
#pragma unroll
          for (int cc = 0; cc < 8; cc++) acc[px][cc] += iv * w8[cc];
        }
      }
    }
  }
#pragma unroll
  for (int px = 0; px < 2; px++) {
    float* yp = y + ((b * H + h) * Wd + w0 + px) * Cout + co;
#pragma unroll
    for (int cc = 0; cc < 8; cc++)
      yp[cc] = fmaxf(acc[px][cc] + bias[co + cc], 0.0f);
  }
}

// ---------------- 128x128 tiled SGEMM, 8x8 per thread ----------------------
__global__ __launch_bounds__(256) void sgemm128(
    const float* __restrict__ A, int lda,
    const float* __restrict__ Bm, int ldb,
    void* __restrict__ C, int ldc,
    const float* __restrict__ bias,
    const float* __restrict__ Dadd, int ldd,
    int M, int N, int K, int amode, int cmode,
    const int* __restrict__ labels, const float* __restrict__ emb)
{
  __shared__ float As[8][132];
  __shared__ float Bs[8][132];
  int tid = threadIdx.x;
  int m0 = blockIdx.y * 128, n0 = blockIdx.x * 128;
  int tx = tid & 15, ty = tid >> 4;
  float acc[8][8];
#pragma unroll
  for (int i = 0; i < 8; i++)
#pragma unroll
    for (int j = 0; j < 8; j++) acc[i][j] = 0.0f;
  int arow = tid >> 1, ak = (tid & 1) * 4;
  int bkr = tid >> 5, bn = (tid & 31) * 4;
  for (int k0 = 0; k0 < K; k0 += 8) {
    float4 av = make_float4(0.f, 0.f, 0.f, 0.f);
    int row = m0 + arow;
    if (row < M) {
      const float* ap;
      if (amode == 0) {
        ap = A + (size_t)row * lda + k0 + ak;
      } else {
        int t = row >> 4, b = row & 15;
        ap = emb + labels[b * TLAB + t] * 80 + k0 + ak;
      }
      av = *(const float4*)ap;
    }
    As[ak + 0][arow] = av.x; As[ak + 1][arow] = av.y;
    As[ak + 2][arow] = av.z; As[ak + 3][arow] = av.w;
    {
      float4 bv = make_float4(0.f, 0.f, 0.f, 0.f);
      int col = n0 + bn;
      const float* bp = Bm + (size_t)(k0 + bkr) * ldb + col;
      if (col + 3 < N) {
        bv = *(const float4*)bp;
      } else if (col < N) {
        bv.x = bp[0];
        if (col + 1 < N) bv.y = bp[1];
        if (col + 2 < N) bv.z = bp[2];
      }
      *(float4*)&Bs[bkr][bn] = bv;
    }
    __syncthreads();
#pragma unroll
    for (int kk = 0; kk < 8; kk++) {
      float a[8], b[8];
      *(float4*)&a[0] = *(const float4*)&As[kk][ty * 8];
      *(float4*)&a[4] = *(const float4*)&As[kk][ty * 8 + 4];
      *(float4*)&b[0] = *(const float4*)&Bs[kk][tx * 8];
      *(float4*)&b[4] = *(const float4*)&Bs[kk][tx * 8 + 4];
#pragma unroll
      for (int i = 0; i < 8; i++)
#pragma unroll
        for (int j = 0; j < 8; j++) acc[i][j] += a[i] * b[j];
    }
    __syncthreads();
  }
#pragma unroll
  for (int i = 0; i < 8; i++) {
    int row = m0 + ty * 8 + i;
    if (row >= M) continue;
#pragma unroll
    for (int j = 0; j < 8; j++) {
      int col = n0 + tx * 8 + j;
      if (col >= N) continue;
      float v = acc[i][j];
      if (Dadd) v += Dadd[(size_t)row * ldd + col];
      if (bias) v += bias[col];
      if (cmode == 0) {
        ((float*)C)[(size_t)row * ldc + col] = v;
      } else if (cmode == 1) {
        int t = row >> 4, b2 = row & 15;
        ((float*)C)[((size_t)b2 * TDEC + t) * 504 + col] = v;
      } else if (cmode == 2) {
        ((float*)C)[(size_t)col * ldc + row] = v;
      } else if (cmode == 3) {
        unsigned bits = __float_as_uint(v);
        u16 h = (u16)((bits + 0x8000u) >> 16);
        ((u16*)C)[(size_t)row * ldc + col] = h;
      } else { // cmode 4
        int b2 = row >> 9, l = row & 511;
        unsigned bits = __float_as_uint(v);
        u16 h = (u16)((bits + 0x8000u) >> 16);
        ((u16*)C)[((size_t)(b2 * 512 + col)) * 512 + l] = h;
      }
    }
  }
}

// ---------------- 32x32 tiled transpose ------------------------------------
__global__ __launch_bounds__(256) void transpose32(
    const float* __restrict__ src, int lds_, int M, int N,
    float* __restrict__ dst, int ldd_, int off)
{
  __shared__ float tle[32][33];
  int tid = threadIdx.x;
  int x = tid & 31, y8 = tid >> 5;
  int m0 = blockIdx.y * 32, n0 = blockIdx.x * 32;
#pragma unroll
  for (int p = 0; p < 4; p++) {
    int m = m0 + y8 + p * 8, n = n0 + x;
    if (m < M && n < N) tle[y8 + p * 8][x] = src[(size_t)m * lds_ + n];
  }
  __syncthreads();
#pragma unroll
  for (int p = 0; p < 4; p++) {
    int n = n0 + y8 + p * 8, m = m0 + x;
    if (n < N && m < M) dst[(size_t)n * ldd_ + off + m] = tle[x][y8 + p * 8];
  }
}

// ---------------- persistent encoder: all 64 steps, one dispatch -----------
// h0 == 0 handled analytically (t==0 skips the h@Wh matvec) — henc[0] is
// never read, so no init needed.
__global__ __launch_bounds__(256) void enc_persist(
    const float* __restrict__ Zfw, const float* __restrict__ Zbw,
    const float* __restrict__ Whfw, const float* __restrict__ Whbw,
    float* __restrict__ henc, float* __restrict__ mem,
    unsigned* __restrict__ earr)
{
  __shared__ float WL[16][260];
  __shared__ float hsh[128][130];
  __shared__ float zl[128][17];
  int tid = threadIdx.x;
  int bi = blockIdx.x;
  int dir = bi >> 6, u0 = (bi & 63) * 4;
  const float* Wh = dir ? Whbw : Whfw;
  const float* Z = dir ? Zbw : Zfw;
  {
    const float* src = Wh + (size_t)tid * 1024 + u0;
#pragma unroll
    for (int g = 0; g < 4; g++) {
      float4 w4 = *(const float4*)(src + g * 256);
      WL[g * 4 + 0][tid] = w4.x; WL[g * 4 + 1][tid] = w4.y;
      WL[g * 4 + 2][tid] = w4.z; WL[g * 4 + 3][tid] = w4.w;
    }
  }
  float creg[2] = {0.0f, 0.0f};
  __syncthreads();

  int c2 = tid & 7, q = tid >> 3;
  for (int t = 0; t < 64; t++) {
    int wp = dir ? (63 - t) : t;
    float a0[4], a1[4];
#pragma unroll
    for (int i = 0; i < 4; i++) { a0[i] = 0.f; a1[i] = 0.f; }
    if (t > 0) {
      const float* hsrc = henc + (size_t)t * 65536 + dir * 32768;
#pragma unroll
      for (int half = 0; half < 2; half++) {
        __syncthreads();
#pragma unroll
        for (int i = 0; i < 16; i++) {
          int flat = i * 256 + tid;
          int n = flat >> 5, kq = flat & 31;
          *(float4*)&hsh[n][kq * 4] = *(const float4*)&hsrc[n * 256 + half * 128 + kq * 4];
        }
        __syncthreads();
        int kw = half * 128;
        for (int k4 = 0; k4 < 32; k4++) {
          float4 w0 = *(const float4*)&WL[c2 * 2 + 0][kw + k4 * 4];
          float4 w1 = *(const float4*)&WL[c2 * 2 + 1][kw + k4 * 4];
#pragma unroll
          for (int i = 0; i < 4; i++) {
            float4 h4 = *(const float4*)&hsh[q * 4 + i][k4 * 4];
            a0[i] += h4.x * w0.x + h4.y * w0.y + h4.z * w0.z + h4.w * w0.w;
            a1[i] += h4.x * w1.x + h4.y * w1.y + h4.z * w1.z + h4.w * w1.w;
          }
        }
      }
    }
#pragma unroll
    for (int i = 0; i < 4; i++) {
      zl[q * 4 + i][c2 * 2 + 0] = a0[i];
      zl[q * 4 + i][c2 * 2 + 1] = a1[i];
    }
    __syncthreads();
#pragma unroll
    for (int s2 = 0; s2 < 2; s2++) {
      int s = tid + s2 * 256;
      int n = s >> 2, uj = s & 3;
      int u = u0 + uj;
      size_t zoff = ((size_t)(n * 64 + wp)) * 1024 + u;
      float zi = zl[n][0 + uj] + Z[zoff];
      float zj = zl[n][4 + uj] + Z[zoff + 256];
      float zf = zl[n][8 + uj] + Z[zoff + 512];
      float zo = zl[n][12 + uj] + Z[zoff + 768];
      float cn = sigm(zf + 1.0f) * creg[s2] + sigm(zi) * tanhfast(zj);
      float hn = sigm(zo) * tanhfast(cn);
      creg[s2] = cn;
      if (t < 63)
        stf_cg(&henc[(size_t)(t + 1) * 65536 + dir * 32768 + n * 256 + u], hn);
      int b = n >> 3, hp = n & 7;
      mem[((size_t)(b * 512 + hp * 64 + wp)) * 512 + dir * 256 + u] = hn;
    }
    if (t < 63) {
      asm volatile("s_waitcnt vmcnt(0)" ::: "memory");
      __syncthreads();
      unsigned ep = t + 1;
      if (tid == 0) st_cg(&earr[bi * 32], ep);
      if (tid < 128)
        while (ld_cg(&earr[tid * 32]) < ep) __builtin_amdgcn_s_sleep(2);
      __syncthreads();
      asm volatile("" ::: "memory");
    }
  }
}

// ---------------- persistent decoder barriers (fence-free) -----------------
__device__ __forceinline__ void bar_full(unsigned* arr, unsigned ep) {
  asm volatile("s_waitcnt vmcnt(0)" ::: "memory");
  __syncthreads();
  if (threadIdx.x == 0) st_cg(&arr[blockIdx.x * 32], ep);
  while (ld_cg(&arr[threadIdx.x * 32]) < ep) __builtin_amdgcn_s_sleep(2);
  __syncthreads();
  asm volatile("" ::: "memory");
}
__device__ __forceinline__ void bar_grp(unsigned* arr, int g, unsigned ep) {
  asm volatile("s_waitcnt vmcnt(0)" ::: "memory");
  __syncthreads();
  int tid = threadIdx.x;
  if (tid == 0) st_cg(&arr[blockIdx.x * 32], ep);
  if (tid < 16) {
    int peer = (g & 7) + ((g >> 3) << 7) + (tid << 3);
    while (ld_cg(&arr[peer * 32]) < ep) __builtin_amdgcn_s_sleep(2);
  }
  __syncthreads();
  asm volatile("" ::: "memory");
}

// ---------------- persistent decoder: all 150 steps in one dispatch --------
__global__ __launch_bounds__(256) void dec_persist(
    const float* __restrict__ WcatT, const float* __restrict__ Zemb,
    const float* __restrict__ WqT, const u16* __restrict__ keysB,
    const u16* __restrict__ memBT, const float* __restrict__ vatt,
    float* __restrict__ hist, float* __restrict__ qbuf_t,
    float* __restrict__ scor_t, unsigned* __restrict__ arr)
{
  __shared__ float hl[16][516];   // staged [h|ctx] half: 16 b x 512
  __shared__ float WT[8][1036];   // fp32 Wcat slice: 8 cols x 1024 k
  __shared__ float vbs[512];
  __shared__ float ez[512];
  __shared__ float redw[4];
  __shared__ float zl[16][8];
  __shared__ float cstL[16][2];
  int tid = threadIdx.x;
  int bi = blockIdx.x;
  int bq = (bi & 7) + 8 * (bi >> 7);   // batch group on XCD (bq&7)
  int chunk = (bi >> 3) & 15;

  {
    int c = tid >> 5, lt = tid & 31;
    int u = bi * 2 + (c & 1), g = c >> 1;
    const float* srcw = WcatT + ((size_t)(g * 512 + u)) * 1024;
#pragma unroll
    for (int i = 0; i < 8; i++) {
      int k = i * 128 + lt * 4;
      *(float4*)&WT[c][k] = *(const float4*)&srcw[k];
    }
  }
  if (tid < 128) {
    float4 v4 = ((const float4*)vatt)[tid];
    int d = tid * 4;
    vbs[EZX(d + 0)] = v4.x; vbs[EZX(d + 1)] = v4.y;
    vbs[EZX(d + 2)] = v4.z; vbs[EZX(d + 3)] = v4.w;
  }
  if (tid < 32) cstL[tid >> 1][tid & 1] = 0.0f;
  __syncthreads();

  for (int t = 0; t < TDEC; t++) {
    // ---- CELL ----
    {
      float acc = 0.0f;
      int b = tid >> 4, c = (tid >> 1) & 7, ks = tid & 1;
      if (t > 0) {
        const float* hp = hist + (size_t)(t - 1) * 16384;
#pragma unroll
        for (int half = 0; half < 2; half++) {
          __syncthreads();
#pragma unroll
          for (int it = 0; it < 8; it++) {
            int f4 = it * 256 + tid;
            int sb = f4 >> 7, si = (f4 & 127) * 4;
            *(float4*)&hl[sb][si] = *(const float4*)&hp[sb * 1024 + half * 512 + si];
          }
          __syncthreads();
          const float* wrow = &WT[c][half * 512 + ks * 256];
          const float* hrow = &hl[b][ks * 256];
#pragma unroll 8
          for (int i = 0; i < 64; i++) {
            float4 w4 = *(const float4*)&wrow[i * 4];
            float4 h4 = *(const float4*)&hrow[i * 4];
            acc += w4.x * h4.x + w4.y * h4.y + w4.z * h4.z + w4.w * h4.w;
          }
        }
      }
      acc += __shfl_xor(acc, 1, 64);
      if (ks == 0) {
        int u = bi * 2 + (c & 1), g = c >> 1;
        zl[b][c] = acc + Zemb[(size_t)(t * 16 + b) * 2048 + g * 512 + u];
      }
    }
    __syncthreads();
    if (tid < 32) {
      int b = tid >> 1, uu = tid & 1;
      float zi = zl[b][uu], zj = zl[b][2 + uu], zf = zl[b][4 + uu], zo = zl[b][6 + uu];
      float cold = cstL[b][uu];
      float cn = sigm(zf + 1.0f) * cold + sigm(zi) * tanhfast(zj);
      float hn = sigm(zo) * tanhfast(cn);
      cstL[b][uu] = cn;
      stf_cg(&hist[(size_t)t * 16384 + b * 1024 + bi * 2 + uu], hn);
    }
    bar_full(arr, 4 * t + 1);

    // ---- Q ----
    {
      int jl = tid >> 3, ks = tid & 7;
      int j = chunk * 32 + jl;
      const float* wr = WqT + (size_t)j * 512 + ks * 64;
      const float* hr = hist + (size_t)t * 16384 + bq * 1024 + ks * 64;
      float acc = 0.f;
#pragma unroll
      for (int i = 0; i < 16; i++) {
        float4 w4 = *(const float4*)&wr[i * 4];
        float4 h4 = *(const float4*)&hr[i * 4];
        acc += w4.x * h4.x + w4.y * h4.y + w4.z * h4.z + w4.w * h4.w;
      }
      acc += __shfl_xor(acc, 1, 64);
      acc += __shfl_xor(acc, 2, 64);
      acc += __shfl_xor(acc, 4, 64);
      if (ks == 0) stf_cg(&qbuf_t[(size_t)t * 8192 + bq * 512 + j], acc);
    }
    bar_grp(arr, bq, 4 * t + 2);

    // ---- SCORE ----
    {
      int l = chunk * 32 + (tid >> 3), dk = tid & 7;
      const u16* kp = keysB + ((size_t)(bq * 512 + l)) * 512 + dk * 64;
      const float* qp = qbuf_t + (size_t)t * 8192 + bq * 512 + dk * 64;
      float acc = 0.f;
#pragma unroll
      for (int i = 0; i < 8; i++) {
        uint4 kv = *(const uint4*)(kp + i * 8);
        float4 qa = *(const float4*)(qp + i * 8);
        float4 qb = *(const float4*)(qp + i * 8 + 4);
        int base = i * 64 + dk;
        acc += vbs[base +  0] * tanhfast(bflo(kv.x) + qa.x);
        acc += vbs[base +  8] * tanhfast(bfhi(kv.x) + qa.y);
        acc += vbs[base + 16] * tanhfast(bflo(kv.y) + qa.z);
        acc += vbs[base + 24] * tanhfast(bfhi(kv.y) + qa.w);
        acc += vbs[base + 32] * tanhfast(bflo(kv.z) + qb.x);
        acc += vbs[base + 40] * tanhfast(bfhi(kv.z) + qb.y);
        acc += vbs[base + 48] * tanhfast(bflo(kv.w) + qb.z);
        acc += vbs[base + 56] * tanhfast(bfhi(kv.w) + qb.w);
      }
      acc += __shfl_xor(acc, 1, 64);
      acc += __shfl_xor(acc, 2, 64);
      acc += __shfl_xor(acc, 4, 64);
      if (dk == 0) stf_cg(&scor_t[(size_t)t * 8192 + bq * 512 + l], acc);
    }
    bar_grp(arr, bq, 4 * t + 3);

    // ---- CTX ----
    {
      float2 sv = *(const float2*)&scor_t[(size_t)t * 8192 + bq * 512 + tid * 2];
      float e0 = __expf(sv.x), e1 = __expf(sv.y);
      ez[EZX(tid * 2)] = e0; ez[EZX(tid * 2 + 1)] = e1;
      float s = e0 + e1;
#pragma unroll
      for (int d = 1; d < 64; d <<= 1) s += __shfl_xor(s, d, 64);
      if ((tid & 63) == 0) redw[tid >> 6] = s;
      __syncthreads();
      float den = redw[0] + redw[1] + redw[2] + redw[3];
      int jl = tid >> 3, ls = tid & 7;
      int j = chunk * 32 + jl;
      const u16* mp = memBT + ((size_t)(bq * 512 + j)) * 512 + ls * 64;
      float acc = 0.f;
#pragma unroll
      for (int i = 0; i < 8; i++) {
        uint4 mv = *(const uint4*)(mp + i * 8);
        int base = i * 64 + ls;
        acc += ez[base +  0] * bflo(mv.x);
        acc += ez[base +  8] * bfhi(mv.x);
        acc += ez[base + 16] * bflo(mv.y);
        acc += ez[base + 24] * bfhi(mv.y);
        acc += ez[base + 32] * bflo(mv.z);
        acc += ez[base + 40] * bfhi(mv.z);
        acc += ez[base + 48] * bflo(mv.w);
        acc += ez[base + 56] * bfhi(mv.w);
      }
      acc += __shfl_xor(acc, 1, 64);
      acc += __shfl_xor(acc, 2, 64);
      acc += __shfl_xor(acc, 4, 64);
      if (ls == 0)
        stf_cg(&hist[(size_t)t * 16384 + bq * 1024 + 512 + j], acc / den);
    }
    if (t < TDEC - 1) bar_full(arr, 4 * t + 4);
  }
}

// ---------------------------------------------------------------------------
extern "C" void kernel_launch(void* const* d_in, const int* in_sizes, int n_in,
                              void* d_out, int out_size, void* d_ws, size_t ws_size,
                              hipStream_t stream) {
  (void)in_sizes; (void)n_in; (void)out_size; (void)ws_size;
  const float* inp   = (const float*)d_in[0];
  const int*   labels= (const int*)  d_in[1];
  const float* ck1 = (const float*)d_in[3];
  const float* cb1 = (const float*)d_in[4];
  const float* ck2 = (const float*)d_in[5];
  const float* cb2 = (const float*)d_in[6];
  const float* ck3 = (const float*)d_in[7];
  const float* cb3 = (const float*)d_in[8];
  const float* ck4 = (const float*)d_in[9];
  const float* cb4 = (const float*)d_in[10];
  const float* Wfw = (const float*)d_in[11];
  const float* bfw = (const float*)d_in[12];
  const float* Wbw = (const float*)d_in[13];
  const float* bbw = (const float*)d_in[14];
  const float* Wdec= (const float*)d_in[15];
  const float* bdec= (const float*)d_in[16];
  const float* Wmem= (const float*)d_in[17];
  const float* Wq  = (const float*)d_in[18];
  const float* vatt= (const float*)d_in[19];
  const float* Wattn=(const float*)d_in[20];
  const float* Wout= (const float*)d_in[21];
  const float* bout= (const float*)d_in[22];
  const float* emb = (const float*)d_in[23];
  float* out = (float*)d_out;
  float* ws  = (float*)d_ws;

  // workspace layout (float slots)
  const size_t OFF_P1    = 0;           // p1 / Zfw / Zemb
  const size_t OFF_ZBW   = 8388608;     // p2 / Zbw; decoder-time: qbuf_t/scor_t
  const size_t OFF_QT    = 8388608;
  const size_t OFF_ST    = 9617408;
  const size_t OFF_C3    = 12582912;    // c3 spans [12582912, 20971520)
  const size_t OFF_HIST  = 16777216;    // inside dead c3; henc[0] never read
  const size_t OFF_P4    = 20971520;
  const size_t OFF_MEM   = 25165824;
  const size_t OFF_KEYSB = 29360128;
  const size_t OFF_MEMBT = 31457280;
  const size_t OFF_WCATT = 33554432;
  const size_t OFF_WQT   = 35651584;
  const size_t OFF_WCAT2 = 35913728;
  const size_t OFF_ARR   = 36429824;    // 8192 u32 (dec barrier)
  const size_t OFF_EARR  = 36438016;    // 4096 u32 (enc barrier)

  float* p1    = ws + OFF_P1;
  float* p2    = ws + OFF_ZBW;
  float* c3    = ws + OFF_C3;
  float* p4    = ws + OFF_P4;
  float* Zfw   = ws + OFF_P1;
  float* Zbw   = ws + OFF_ZBW;
  float* Zemb  = ws + OFF_P1;
  float* qbuf_t= ws + OFF_QT;
  float* scor_t= ws + OFF_ST;
  float* hist  = ws + OFF_HIST;
  float* henc  = ws + OFF_HIST;
  float* memv  = ws + OFF_MEM;
  u16*   keysB = (u16*)(ws + OFF_KEYSB);
  u16*   memBT = (u16*)(ws + OFF_MEMBT);
  float* WcatT = ws + OFF_WCATT;
  float* WqT   = ws + OFF_WQT;
  float* Wcat2 = ws + OFF_WCAT2;
  unsigned* arr  = (unsigned*)(ws + OFF_ARR);
  unsigned* earr = (unsigned*)(ws + OFF_EARR);

  hipMemsetAsync(arr, 0, (8192 + 4096) * 4, stream);   // arr + earr contiguous

  // CNN
  conv_pool   <<<4096, 256, 0, stream>>>(inp, ck1, cb1, p1, 64, 512, 1, 64);
  conv_pool2  <<<1024, 256, 0, stream>>>(p1, ck2, cb2, p2, 32, 256, 64, 128);
  conv_nopool2<<<2048, 256, 0, stream>>>(p2, ck3, cb3, c3, 16, 128, 128, 256);
  conv_pool2  <<<1024, 256, 0, stream>>>(c3, ck4, cb4, p4, 16, 128, 256, 512);

  // encoder input-side GEMMs
  sgemm128<<<dim3(8, 64), 256, 0, stream>>>(p4, 512, Wfw, 1024, Zfw, 1024, bfw,
                                            nullptr, 0, 8192, 1024, 512, 0, 0, nullptr, nullptr);
  sgemm128<<<dim3(8, 64), 256, 0, stream>>>(p4, 512, Wbw, 1024, Zbw, 1024, bbw,
                                            nullptr, 0, 8192, 1024, 512, 0, 0, nullptr, nullptr);
  // encoder recurrence: one persistent dispatch
  enc_persist<<<128, 256, 0, stream>>>(Zfw, Zbw, Wfw + 512 * 1024, Wbw + 512 * 1024,
                                       henc, memv, earr);

  // attention precomputes (bf16 outputs for decoder streaming)
  sgemm128<<<dim3(4, 64), 256, 0, stream>>>(memv, 512, Wmem, 512, keysB, 512,
                                            nullptr, nullptr, 0, 8192, 512, 512, 0, 3, nullptr, nullptr);
  sgemm128<<<dim3(4, 64), 256, 0, stream>>>(memv, 512, Wattn + 512 * 512, 512, memBT, 512,
                                            nullptr, nullptr, 0, 8192, 512, 512, 0, 4, nullptr, nullptr);
  // WcatT upper: (W1@Wdec_a + Wdec_h)^T
  sgemm128<<<dim3(16, 4), 256, 0, stream>>>(Wattn, 512, Wdec + 80 * 2048, 2048, WcatT, 1024,
                                            nullptr, Wdec + 592 * 2048, 2048,
                                            512, 2048, 512, 0, 2, nullptr, nullptr);
  // WcatT lower: Wdec_a^T
  transpose32<<<dim3(64, 16), 256, 0, stream>>>(Wdec + 80 * 2048, 2048, 512, 2048, WcatT, 1024, 512);
  // WqT
  transpose32<<<dim3(16, 16), 256, 0, stream>>>(Wq, 512, 512, 512, WqT, 512, 0);
  // Wcat2
  sgemm128<<<dim3(4, 4), 256, 0, stream>>>(Wattn, 512, Wout, 504, Wcat2, 504,
                                           nullptr, nullptr, 0, 512, 504, 512, 0, 0, nullptr, nullptr);
  hipMemcpyAsync(Wcat2 + 512 * 504, Wout, (size_t)512 * 504 * 4, hipMemcpyDeviceToDevice, stream);
  // Zemb
  sgemm128<<<dim3(16, 19), 256, 0, stream>>>(nullptr, 0, Wdec, 2048, Zemb, 2048, bdec,
                                             nullptr, 0, 2400, 2048, 80, 1, 0, labels, emb);

  // decoder: one persistent dispatch
  dec_persist<<<256, 256, 0, stream>>>(WcatT, Zemb, WqT, keysB, memBT, vatt,
                                       hist, qbuf_t, scor_t, arr);

  // logits
  sgemm128<<<dim3(4, 19), 256, 0, stream>>>(hist, 1024, Wcat2, 504, out, 504, bout,
                                            nullptr, 0, 2400, 504, 1024, 0, 1, nullptr, nullptr);
}